// Round 6
// baseline (256.950 us; speedup 1.0000x reference)
//
#include <hip/hip_runtime.h>
#include <hip/hip_bf16.h>

typedef __bf16 bf16_t;
typedef __bf16 bf16x8 __attribute__((ext_vector_type(8)));
typedef __bf16 bf16x4 __attribute__((ext_vector_type(4)));
typedef float  f32x4  __attribute__((ext_vector_type(4)));

#define SEQ    2048
#define BATCH  2
#define NHEAD  16
#define HDIM   64
#define DMODEL 1024
#define WIN    256
// 0.125 (1/sqrt(64)) * log2(e): folded into Q so softmax exp is a bare v_exp_f32
#define QSCALE 0.1803368801111244f

// async global->LDS, 16B per lane (dest = wave-uniform base + lane*16).
__device__ __forceinline__ void async_load16(const void* g, void* l) {
    __builtin_amdgcn_global_load_lds(
        (const __attribute__((address_space(1))) char*)(uintptr_t)g,
        (__attribute__((address_space(3))) char*)(uintptr_t)l, 16, 0, 0);
}

// ---------------------------------------------------------------------------
// Kernel 1: cast x (fp32) -> bf16, flat [4096][1024]
// ---------------------------------------------------------------------------
__global__ void cast_x_kernel(const float* __restrict__ x, bf16_t* __restrict__ xb, int n4) {
    int i = blockIdx.x * blockDim.x + threadIdx.x;
    if (i >= n4) return;
    float4 v = ((const float4*)x)[i];
    bf16x4 o;
    o[0] = (bf16_t)v.x; o[1] = (bf16_t)v.y; o[2] = (bf16_t)v.z; o[3] = (bf16_t)v.w;
    ((bf16x4*)xb)[i] = o;
}

// ---------------------------------------------------------------------------
// Kernel 2: transpose+cast weights into Wt[4][1024][1024] (B^T layout)
// ---------------------------------------------------------------------------
__global__ void transpose_w_kernel(const float* __restrict__ Wq, const float* __restrict__ Wk,
                                   const float* __restrict__ Wv, const float* __restrict__ Wo,
                                   bf16_t* __restrict__ Wt) {
    __shared__ float tile[32][33];
    const float* W = (blockIdx.z == 0) ? Wq : (blockIdx.z == 1) ? Wk : (blockIdx.z == 2) ? Wv : Wo;
    bf16_t* out = Wt + (size_t)blockIdx.z * DMODEL * DMODEL;
    int k0 = blockIdx.y * 32, n0 = blockIdx.x * 32;
    int tx = threadIdx.x, ty = threadIdx.y;  // block (32, 8)
#pragma unroll
    for (int i = 0; i < 4; i++)
        tile[ty + i * 8][tx] = W[(size_t)(k0 + ty + i * 8) * DMODEL + n0 + tx];
    __syncthreads();
#pragma unroll
    for (int i = 0; i < 4; i++)
        out[(size_t)(n0 + ty + i * 8) * DMODEL + k0 + tx] = (bf16_t)tile[tx][ty + i * 8];
}

// ---------------------------------------------------------------------------
// Kernel 3: V transpose, Vb[B,H,S,64] -> Vt[B,H,64,S]. Block (64,4), 64x64 tile.
// ---------------------------------------------------------------------------
__global__ __launch_bounds__(256) void vtrans_kernel(const bf16_t* __restrict__ Vb,
                                                     bf16_t* __restrict__ Vt) {
    __shared__ bf16_t tile[64][65];
    const int bh = blockIdx.y, s0 = blockIdx.x * 64;
    const int tx = threadIdx.x, ty = threadIdx.y;
    const bf16_t* src = Vb + ((size_t)bh * SEQ + s0) * HDIM;
    bf16_t* dst = Vt + (size_t)bh * HDIM * SEQ + s0;
#pragma unroll
    for (int i = 0; i < 16; i++) {
        int row = i * 4 + ty;
        tile[row][tx] = src[(size_t)row * HDIM + tx];      // coalesced
    }
    __syncthreads();
#pragma unroll
    for (int i = 0; i < 16; i++) {
        int d = i * 4 + ty;
        dst[(size_t)d * SEQ + tx] = tile[tx][d];           // coalesced
    }
}

// ---------------------------------------------------------------------------
// GEMM (flatmm-shape): C = A * Bt^T. A tile (BM x 64) staged in LDS via
// swizzled global_load_lds; B fragments streamed DIRECTLY from global (L2-hot
// per-XCD thanks to n-strip swizzle) -> halves LDS-pipe load vs both-in-LDS.
// 4 waves arranged 4/CW rows x CW cols; per-wave tile (IM*16) x (JN*16).
// EPI 0: QKV epilogue -> Qb(QSCALE)/Kb/Vb all [B,H,S,64]. EPI 1: Out=acc+bo.
// ---------------------------------------------------------------------------
template <int EPI, int BM, int IM, int JN, int CW>
__global__ __launch_bounds__(256) void gemm_bt_kernel(
    const bf16_t* __restrict__ A, const bf16_t* __restrict__ Bt,
    bf16_t* __restrict__ Qb, bf16_t* __restrict__ Kb, bf16_t* __restrict__ Vb,
    float* __restrict__ Out, const float* __restrict__ bo, int K, int nPer) {
    __shared__ __attribute__((aligned(16))) bf16_t As[BM * 64];
    const int tid = threadIdx.x;
    const int wave = tid >> 6, lane = tid & 63, quad = lane >> 4, l15 = lane & 15;
    const int wm = wave / CW, wn = wave % CW;
    // XCD swizzle: id&7 = XCD; each XCD owns an nPer-wide n-strip.
    const int id = blockIdx.x, xcd = id & 7, t = id >> 3;
    const int m0 = (t / nPer) * BM, n0 = (xcd * nPer + t % nPer) * 128;

    f32x4 acc[IM][JN] = {};

    for (int kt = 0; kt < K; kt += 64) {
        // stage A tile (BM x 64), XOR chunk swizzle
#pragma unroll
        for (int i = 0; i < BM / 32; i++) {
            int v = tid + i * 256;
            int row = v >> 3, c = (v & 7) ^ (row & 7);
            async_load16(A + (size_t)(m0 + row) * K + kt + c * 8, (char*)As + (size_t)v * 16);
        }
        __syncthreads();
#pragma unroll
        for (int kk = 0; kk < 64; kk += 32) {
            bf16x8 am[IM], bn[JN];
#pragma unroll
            for (int i = 0; i < IM; i++) {
                int row = wm * IM * 16 + i * 16 + l15;
                int ch = ((kk >> 3) + quad) ^ (row & 7);
                am[i] = *(const bf16x8*)&As[row * 64 + ch * 8];
            }
#pragma unroll
            for (int j = 0; j < JN; j++) {
                int n = n0 + wn * JN * 16 + j * 16 + l15;
                bn[j] = *(const bf16x8*)(Bt + (size_t)n * K + kt + kk + quad * 8);
            }
#pragma unroll
            for (int i = 0; i < IM; i++)
#pragma unroll
                for (int j = 0; j < JN; j++)
                    acc[i][j] = __builtin_amdgcn_mfma_f32_16x16x32_bf16(am[i], bn[j], acc[i][j], 0, 0, 0);
        }
        __syncthreads();
    }

#pragma unroll
    for (int i = 0; i < IM; i++)
#pragma unroll
        for (int j = 0; j < JN; j++)
#pragma unroll
            for (int r = 0; r < 4; r++) {
                int mg = m0 + wm * IM * 16 + i * 16 + quad * 4 + r;
                int ng = n0 + wn * JN * 16 + j * 16 + l15;
                float v = acc[i][j][r];
                if (EPI == 0) {
                    int sel = ng >> 10, nl = ng & 1023, h = nl >> 6, d = nl & 63;
                    int b = mg >> 11, s = mg & 2047;
                    size_t idx = ((size_t)((b * NHEAD + h) * SEQ) + s) * HDIM + d;
                    if (sel == 0)      Qb[idx] = (bf16_t)(v * QSCALE);
                    else if (sel == 1) Kb[idx] = (bf16_t)v;
                    else               Vb[idx] = (bf16_t)v;
                } else {
                    Out[(size_t)mg * DMODEL + ng] = v + bo[ng];
                }
            }
}

// ---------------------------------------------------------------------------
// Attention v5: NO K/V LDS staging, NO barriers. K and V^T fragments are read
// directly from global as B-operands (16 rows x 64B pattern, L2/L1-hot: all 4
// waves of a block read identical K/V addresses; per-XCD footprint 2 MB).
// Only the per-wave-private P C->A layout roundtrip uses LDS. exp2 softmax
// (scale folded into Q); denominator via ones-MFMA row-sum.
// ---------------------------------------------------------------------------
__global__ __launch_bounds__(256) void attn_kernel(
    const bf16_t* __restrict__ Qb, const bf16_t* __restrict__ Kb,
    const bf16_t* __restrict__ Vt, bf16_t* __restrict__ ctx) {
    __shared__ __attribute__((aligned(16))) bf16_t Plds[4][16][72];
    const int tid = threadIdx.x;
    const int wave = tid >> 6, lane = tid & 63, quad = lane >> 4, l15 = lane & 15;

    // XCD-aware task swizzle: 1024 blocks, 128 consecutive tasks per XCD
    // (= 4 heads -> 2 MB K/V per XCD L2).
    const int id = blockIdx.x;
    const int task = (id & 7) * 128 + (id >> 3);
    const int b = task >> 9, h = (task >> 5) & 15, q0 = (task & 31) << 6;
    const int qbase = q0 + wave * 16;

    const bf16_t* Qp = Qb + (size_t)(b * NHEAD + h) * SEQ * HDIM;
    const bf16_t* Kp = Kb + (size_t)(b * NHEAD + h) * SEQ * HDIM;
    const bf16_t* Vp = Vt + (size_t)(b * NHEAD + h) * HDIM * SEQ;

    bf16x8 qa0 = *(const bf16x8*)(Qp + (size_t)(qbase + l15) * HDIM + quad * 8);
    bf16x8 qa1 = *(const bf16x8*)(Qp + (size_t)(qbase + l15) * HDIM + 32 + quad * 8);

    bf16x8 ones;
#pragma unroll
    for (int j = 0; j < 8; j++) ones[j] = (bf16_t)1.0f;

    f32x4 O[4] = {};
    f32x4 lacc = {};

    const int qt = q0 >> 6;
    const int t0 = (qt - 4 > 0) ? qt - 4 : 0;
    const int t1 = (qt + 4 < SEQ / 64 - 1) ? qt + 4 : SEQ / 64 - 1;

    for (int kt = t0; kt <= t1; kt++) {
        const int k0 = kt * 64;
        f32x4 s[4];
#pragma unroll
        for (int c = 0; c < 4; c++) {
            const bf16_t* kr = Kp + (size_t)(k0 + c * 16 + l15) * HDIM;
            bf16x8 kb0 = *(const bf16x8*)(kr + quad * 8);
            bf16x8 kb1 = *(const bf16x8*)(kr + 32 + quad * 8);
            f32x4 a = {};
            a = __builtin_amdgcn_mfma_f32_16x16x32_bf16(qa0, kb0, a, 0, 0, 0);
            a = __builtin_amdgcn_mfma_f32_16x16x32_bf16(qa1, kb1, a, 0, 0, 0);
            s[c] = a;
        }
        const int dt = kt - qt;
        const bool edge = (dt <= -4 || dt >= 4);
#pragma unroll
        for (int c = 0; c < 4; c++)
#pragma unroll
            for (int r = 0; r < 4; r++) {
                float sv = s[c][r];
                if (edge) {
                    int i = qbase + quad * 4 + r;
                    int j = k0 + c * 16 + l15;
                    int dd = i - j; dd = (dd < 0) ? -dd : dd;
                    if (dd > WIN) sv = -1e30f;
                }
                Plds[wave][quad * 4 + r][c * 16 + l15] = (bf16_t)__builtin_exp2f(sv);
            }
        bf16x8 pa0 = *(const bf16x8*)&Plds[wave][l15][quad * 8];
        bf16x8 pa1 = *(const bf16x8*)&Plds[wave][l15][32 + quad * 8];
        lacc = __builtin_amdgcn_mfma_f32_16x16x32_bf16(pa0, ones, lacc, 0, 0, 0);
        lacc = __builtin_amdgcn_mfma_f32_16x16x32_bf16(pa1, ones, lacc, 0, 0, 0);
#pragma unroll
        for (int d = 0; d < 4; d++) {
            const bf16_t* vr = Vp + (size_t)(d * 16 + l15) * SEQ + k0;
            bf16x8 vb0 = *(const bf16x8*)(vr + quad * 8);
            bf16x8 vb1 = *(const bf16x8*)(vr + 32 + quad * 8);
            O[d] = __builtin_amdgcn_mfma_f32_16x16x32_bf16(pa0, vb0, O[d], 0, 0, 0);
            O[d] = __builtin_amdgcn_mfma_f32_16x16x32_bf16(pa1, vb1, O[d], 0, 0, 0);
        }
    }

#pragma unroll
    for (int r = 0; r < 4; r++) {
        float inv = 1.0f / lacc[r];
        int i = qbase + quad * 4 + r;
#pragma unroll
        for (int d = 0; d < 4; d++) {
            float v = O[d][r] * inv;
            ctx[((size_t)(b * SEQ + i)) * DMODEL + h * HDIM + d * 16 + l15] = (bf16_t)v;
        }
    }
}

// ---------------------------------------------------------------------------
extern "C" void kernel_launch(void* const* d_in, const int* in_sizes, int n_in,
                              void* d_out, int out_size, void* d_ws, size_t ws_size,
                              hipStream_t stream) {
    const float* x  = (const float*)d_in[0];
    const float* Wq = (const float*)d_in[1];
    const float* Wk = (const float*)d_in[2];
    const float* Wv = (const float*)d_in[3];
    const float* Wo = (const float*)d_in[4];
    const float* bo = (const float*)d_in[5];
    float* out = (float*)d_out;

    const size_t MTOK = (size_t)BATCH * SEQ;          // 4096
    bf16_t* xb  = (bf16_t*)d_ws;                      // 4096*1024
    bf16_t* Wt  = xb + MTOK * DMODEL;                 // 4*1024*1024
    bf16_t* Qb  = Wt + (size_t)4 * DMODEL * DMODEL;   // [B,H,S,64]
    bf16_t* Kb  = Qb + MTOK * DMODEL;                 // [B,H,S,64]
    bf16_t* Vt  = Kb + MTOK * DMODEL;                 // [B,H,64,S]
    bf16_t* ctx = Vt + MTOK * DMODEL;                 // [4096][1024]
    bf16_t* Vb  = ctx;  // alias: Vb dead before attn writes ctx

    cast_x_kernel<<<dim3((MTOK * DMODEL / 4 + 255) / 256), dim3(256), 0, stream>>>(
        x, xb, (int)(MTOK * DMODEL / 4));
    transpose_w_kernel<<<dim3(32, 32, 4), dim3(32, 8), 0, stream>>>(Wq, Wk, Wv, Wo, Wt);
    // QKV: M=4096, N=3072, K=1024; BM=128, waves 2x2 (64x64 each), 3 strips/XCD
    gemm_bt_kernel<0, 128, 4, 4, 2><<<dim3(768), dim3(256), 0, stream>>>(
        xb, Wt, Qb, Kb, Vb, nullptr, nullptr, DMODEL, 3);
    vtrans_kernel<<<dim3(32, 32), dim3(64, 4), 0, stream>>>(Vb, Vt);
    attn_kernel<<<dim3(1024), dim3(256), 0, stream>>>(Qb, Kb, Vt, ctx);
    // Out: M=4096, N=1024, K=1024; BM=64, waves 1x4 (64x32 each), 1 strip/XCD
    gemm_bt_kernel<1, 64, 4, 2, 4><<<dim3(512), dim3(256), 0, stream>>>(
        ctx, Wt + (size_t)3 * DMODEL * DMODEL, nullptr, nullptr, nullptr, out, bo, DMODEL, 1);
}

// Round 7
// 174.359 us; speedup vs baseline: 1.4737x; 1.4737x over previous
//
#include <hip/hip_runtime.h>
#include <hip/hip_bf16.h>

typedef __bf16 bf16_t;
typedef __bf16 bf16x8 __attribute__((ext_vector_type(8)));
typedef __bf16 bf16x4 __attribute__((ext_vector_type(4)));
typedef float  f32x4  __attribute__((ext_vector_type(4)));

#define SEQ    2048
#define BATCH  2
#define NHEAD  16
#define HDIM   64
#define DMODEL 1024
#define WIN    256
// 0.125 (1/sqrt(64)) * log2(e): folded into Q so softmax exp is one v_exp_f32
#define QSCALE 0.1803368801111244f

// async global->LDS, 16B per lane (dest = wave-uniform base + lane*16).
__device__ __forceinline__ void async_load16(const void* g, void* l) {
    __builtin_amdgcn_global_load_lds(
        (const __attribute__((address_space(1))) char*)(uintptr_t)g,
        (__attribute__((address_space(3))) char*)(uintptr_t)l, 16, 0, 0);
}

// ---------------------------------------------------------------------------
// Kernel 1: cast x (fp32) -> bf16, flat [4096][1024]
// ---------------------------------------------------------------------------
__global__ void cast_x_kernel(const float* __restrict__ x, bf16_t* __restrict__ xb, int n4) {
    int i = blockIdx.x * blockDim.x + threadIdx.x;
    if (i >= n4) return;
    float4 v = ((const float4*)x)[i];
    bf16x4 o;
    o[0] = (bf16_t)v.x; o[1] = (bf16_t)v.y; o[2] = (bf16_t)v.z; o[3] = (bf16_t)v.w;
    ((bf16x4*)xb)[i] = o;
}

// ---------------------------------------------------------------------------
// Kernel 2: transpose+cast weights into Wt[4][1024][1024] (B^T layout)
// ---------------------------------------------------------------------------
__global__ void transpose_w_kernel(const float* __restrict__ Wq, const float* __restrict__ Wk,
                                   const float* __restrict__ Wv, const float* __restrict__ Wo,
                                   bf16_t* __restrict__ Wt) {
    __shared__ float tile[32][33];
    const float* W = (blockIdx.z == 0) ? Wq : (blockIdx.z == 1) ? Wk : (blockIdx.z == 2) ? Wv : Wo;
    bf16_t* out = Wt + (size_t)blockIdx.z * DMODEL * DMODEL;
    int k0 = blockIdx.y * 32, n0 = blockIdx.x * 32;
    int tx = threadIdx.x, ty = threadIdx.y;  // block (32, 8)
#pragma unroll
    for (int i = 0; i < 4; i++)
        tile[ty + i * 8][tx] = W[(size_t)(k0 + ty + i * 8) * DMODEL + n0 + tx];
    __syncthreads();
#pragma unroll
    for (int i = 0; i < 4; i++)
        out[(size_t)(n0 + ty + i * 8) * DMODEL + k0 + tx] = (bf16_t)tile[tx][ty + i * 8];
}

// ---------------------------------------------------------------------------
// Kernel 3: V transpose, Vb[B,H,S,64] -> Vt[B,H,64,S]. Block (64,4), 64x64 tile.
// ---------------------------------------------------------------------------
__global__ __launch_bounds__(256) void vtrans_kernel(const bf16_t* __restrict__ Vb,
                                                     bf16_t* __restrict__ Vt) {
    __shared__ bf16_t tile[64][65];
    const int bh = blockIdx.y, s0 = blockIdx.x * 64;
    const int tx = threadIdx.x, ty = threadIdx.y;
    const bf16_t* src = Vb + ((size_t)bh * SEQ + s0) * HDIM;
    bf16_t* dst = Vt + (size_t)bh * HDIM * SEQ + s0;
#pragma unroll
    for (int i = 0; i < 16; i++) {
        int row = i * 4 + ty;
        tile[row][tx] = src[(size_t)row * HDIM + tx];      // coalesced
    }
    __syncthreads();
#pragma unroll
    for (int i = 0; i < 16; i++) {
        int d = i * 4 + ty;
        dst[(size_t)d * SEQ + tx] = tile[tx][d];           // coalesced
    }
}

// ---------------------------------------------------------------------------
// GEMM (r4 structure): C = A * Bt^T, 128x128 tile, BOTH A and B staged in LDS
// via swizzled global_load_lds (XOR chunk swizzle -> 0 bank conflicts).
// 1D grid, XCD n-strip swizzle (id&7). EPI 0: QKV -> Qb(QSCALE)/Kb/Vb
// [B,H,S,64]. EPI 1: Out = acc + bo.
// ---------------------------------------------------------------------------
template <int EPI>
__global__ __launch_bounds__(256) void gemm_bt_kernel(
    const bf16_t* __restrict__ A, const bf16_t* __restrict__ Bt,
    bf16_t* __restrict__ Qb, bf16_t* __restrict__ Kb, bf16_t* __restrict__ Vb,
    float* __restrict__ Out, const float* __restrict__ bo, int K, int nPer) {
    __shared__ __attribute__((aligned(16))) bf16_t As[128 * 64];
    __shared__ __attribute__((aligned(16))) bf16_t Bs[128 * 64];
    const int tid = threadIdx.x;
    const int wave = tid >> 6, lane = tid & 63, quad = lane >> 4, l15 = lane & 15;
    const int wm = wave >> 1, wn = wave & 1;
    const int id = blockIdx.x, xcd = id & 7, t = id >> 3;
    const int m0 = (t / nPer) * 128, n0 = (xcd * nPer + t % nPer) * 128;

    f32x4 acc[4][4] = {};

    for (int kt = 0; kt < K; kt += 64) {
#pragma unroll
        for (int i = 0; i < 4; i++) {
            int v = tid + i * 256;           // 1024 chunks of 16B per matrix
            int row = v >> 3, c = (v & 7) ^ (row & 7);
            async_load16(A + (size_t)(m0 + row) * K + kt + c * 8, (char*)As + (size_t)v * 16);
            async_load16(Bt + (size_t)(n0 + row) * K + kt + c * 8, (char*)Bs + (size_t)v * 16);
        }
        __syncthreads();
#pragma unroll
        for (int kk = 0; kk < 64; kk += 32) {
            bf16x8 am[4], bn[4];
#pragma unroll
            for (int i = 0; i < 4; i++) {
                int row = wm * 64 + i * 16 + l15;
                int ch = ((kk >> 3) + quad) ^ (row & 7);
                am[i] = *(const bf16x8*)&As[row * 64 + ch * 8];
            }
#pragma unroll
            for (int j = 0; j < 4; j++) {
                int row = wn * 64 + j * 16 + l15;
                int ch = ((kk >> 3) + quad) ^ (row & 7);
                bn[j] = *(const bf16x8*)&Bs[row * 64 + ch * 8];
            }
#pragma unroll
            for (int i = 0; i < 4; i++)
#pragma unroll
                for (int j = 0; j < 4; j++)
                    acc[i][j] = __builtin_amdgcn_mfma_f32_16x16x32_bf16(am[i], bn[j], acc[i][j], 0, 0, 0);
        }
        __syncthreads();
    }

#pragma unroll
    for (int i = 0; i < 4; i++)
#pragma unroll
        for (int j = 0; j < 4; j++)
#pragma unroll
            for (int r = 0; r < 4; r++) {
                int mg = m0 + wm * 64 + i * 16 + quad * 4 + r;
                int ng = n0 + wn * 64 + j * 16 + l15;
                float v = acc[i][j][r];
                if (EPI == 0) {
                    int sel = ng >> 10, nl = ng & 1023, h = nl >> 6, d = nl & 63;
                    int b = mg >> 11, s = mg & 2047;
                    size_t idx = ((size_t)((b * NHEAD + h) * SEQ) + s) * HDIM + d;
                    if (sel == 0)      Qb[idx] = (bf16_t)(v * QSCALE);
                    else if (sel == 1) Kb[idx] = (bf16_t)v;
                    else               Vb[idx] = (bf16_t)v;
                } else {
                    Out[(size_t)mg * DMODEL + ng] = v + bo[ng];
                }
            }
}

// ---------------------------------------------------------------------------
// Attention (r4 structure, identity task mapping): 512 threads, 2 query-tiles
// (128 q) per block; block stages union window (10 K/V tiles) in double-
// buffered LDS, each wave computes its 9 in-window tiles. IDENTITY mapping:
// consecutive block ids = consecutive q-tiles of one head -> if XCD assignment
// is contiguous-chunked, each XCD sees ~4 heads (1.5 MB) of K/V.
// exp2 softmax (scale folded into Q); denominator via ones-MFMA row-sum.
// ---------------------------------------------------------------------------
__global__ __launch_bounds__(512) void attn_kernel(
    const bf16_t* __restrict__ Qb, const bf16_t* __restrict__ Kb,
    const bf16_t* __restrict__ Vt, bf16_t* __restrict__ ctx) {
    __shared__ __attribute__((aligned(16))) bf16_t Ks[2][64 * 64];
    __shared__ __attribute__((aligned(16))) bf16_t Vs[2][64 * 64];
    __shared__ __attribute__((aligned(16))) bf16_t Plds[8][16][72];
    const int tid = threadIdx.x;
    const int wave = tid >> 6, lane = tid & 63, quad = lane >> 4, l15 = lane & 15;

    // identity mapping: id = b(1) | h(4) | qpair(4)
    const int id = blockIdx.x;
    const int b = id >> 8, h = (id >> 4) & 15, Q0 = (id & 15) << 7;
    const int qbase = Q0 + wave * 16;
    const int wqt = (Q0 >> 6) + (wave >> 2);   // this wave's 64-aligned q-tile

    const bf16_t* Qp = Qb + (size_t)(b * NHEAD + h) * SEQ * HDIM;
    const bf16_t* Kp = Kb + (size_t)(b * NHEAD + h) * SEQ * HDIM;
    const bf16_t* Vp = Vt + (size_t)(b * NHEAD + h) * HDIM * SEQ;

    bf16x8 qa0 = *(const bf16x8*)(Qp + (size_t)(qbase + l15) * HDIM + quad * 8);
    bf16x8 qa1 = *(const bf16x8*)(Qp + (size_t)(qbase + l15) * HDIM + 32 + quad * 8);

    bf16x8 ones;
#pragma unroll
    for (int j = 0; j < 8; j++) ones[j] = (bf16_t)1.0f;

    f32x4 O[4] = {};
    f32x4 lacc = {};

    const int base_t = Q0 >> 6;
    const int bt0 = (base_t - 4 > 0) ? base_t - 4 : 0;
    const int bt1 = (base_t + 5 < SEQ / 64 - 1) ? base_t + 5 : SEQ / 64 - 1;

    auto stage = [&](int kt, int buf) {
        const int k0 = kt * 64;
        int v = tid;                          // 512 chunks of 16B each
        int row = v >> 3, c = (v & 7) ^ (row & 7);
        async_load16(Kp + (size_t)(k0 + row) * HDIM + c * 8, (char*)&Ks[buf][0] + (size_t)v * 16);
        async_load16(Vp + (size_t)row * SEQ + k0 + c * 8, (char*)&Vs[buf][0] + (size_t)v * 16);
    };

    stage(bt0, 0);
    int cb = 0;
    for (int kt = bt0; kt <= bt1; kt++) {
        __syncthreads();                       // staging of current tile complete
        if (kt < bt1) stage(kt + 1, cb ^ 1);   // prefetch next during compute
        const int dt = kt - wqt;
        if (dt >= -4 && dt <= 4) {             // wave-uniform window check
            const int k0 = kt * 64;
            f32x4 s[4];
#pragma unroll
            for (int c = 0; c < 4; c++) {
                int row = c * 16 + l15;
                bf16x8 kb0 = *(const bf16x8*)&Ks[cb][row * 64 + (quad ^ (row & 7)) * 8];
                bf16x8 kb1 = *(const bf16x8*)&Ks[cb][row * 64 + ((quad + 4) ^ (row & 7)) * 8];
                f32x4 a = {};
                a = __builtin_amdgcn_mfma_f32_16x16x32_bf16(qa0, kb0, a, 0, 0, 0);
                a = __builtin_amdgcn_mfma_f32_16x16x32_bf16(qa1, kb1, a, 0, 0, 0);
                s[c] = a;
            }
            const bool edge = (dt == -4 || dt == 4);
#pragma unroll
            for (int c = 0; c < 4; c++)
#pragma unroll
                for (int r = 0; r < 4; r++) {
                    float sv = s[c][r];
                    if (edge) {
                        int i = qbase + quad * 4 + r;
                        int j = k0 + c * 16 + l15;
                        int dd = i - j; dd = (dd < 0) ? -dd : dd;
                        if (dd > WIN) sv = -1e30f;
                    }
                    Plds[wave][quad * 4 + r][c * 16 + l15] = (bf16_t)__builtin_exp2f(sv);
                }
            bf16x8 pa0 = *(const bf16x8*)&Plds[wave][l15][quad * 8];
            bf16x8 pa1 = *(const bf16x8*)&Plds[wave][l15][32 + quad * 8];
            lacc = __builtin_amdgcn_mfma_f32_16x16x32_bf16(pa0, ones, lacc, 0, 0, 0);
            lacc = __builtin_amdgcn_mfma_f32_16x16x32_bf16(pa1, ones, lacc, 0, 0, 0);
#pragma unroll
            for (int d = 0; d < 4; d++) {
                int row = d * 16 + l15;
                bf16x8 vb0 = *(const bf16x8*)&Vs[cb][row * 64 + (quad ^ (row & 7)) * 8];
                bf16x8 vb1 = *(const bf16x8*)&Vs[cb][row * 64 + ((quad + 4) ^ (row & 7)) * 8];
                O[d] = __builtin_amdgcn_mfma_f32_16x16x32_bf16(pa0, vb0, O[d], 0, 0, 0);
                O[d] = __builtin_amdgcn_mfma_f32_16x16x32_bf16(pa1, vb1, O[d], 0, 0, 0);
            }
        }
        __syncthreads();                       // all waves done with cb before reuse
        cb ^= 1;
    }

#pragma unroll
    for (int r = 0; r < 4; r++) {
        float inv = 1.0f / lacc[r];
        int i = qbase + quad * 4 + r;
#pragma unroll
        for (int d = 0; d < 4; d++) {
            float v = O[d][r] * inv;
            ctx[((size_t)(b * SEQ + i)) * DMODEL + h * HDIM + d * 16 + l15] = (bf16_t)v;
        }
    }
}

// ---------------------------------------------------------------------------
extern "C" void kernel_launch(void* const* d_in, const int* in_sizes, int n_in,
                              void* d_out, int out_size, void* d_ws, size_t ws_size,
                              hipStream_t stream) {
    const float* x  = (const float*)d_in[0];
    const float* Wq = (const float*)d_in[1];
    const float* Wk = (const float*)d_in[2];
    const float* Wv = (const float*)d_in[3];
    const float* Wo = (const float*)d_in[4];
    const float* bo = (const float*)d_in[5];
    float* out = (float*)d_out;

    const size_t MTOK = (size_t)BATCH * SEQ;          // 4096
    bf16_t* xb  = (bf16_t*)d_ws;                      // 4096*1024
    bf16_t* Wt  = xb + MTOK * DMODEL;                 // 4*1024*1024
    bf16_t* Qb  = Wt + (size_t)4 * DMODEL * DMODEL;   // [B,H,S,64]
    bf16_t* Kb  = Qb + MTOK * DMODEL;                 // [B,H,S,64]
    bf16_t* Vt  = Kb + MTOK * DMODEL;                 // [B,H,64,S]
    bf16_t* ctx = Vt + MTOK * DMODEL;                 // [4096][1024]
    bf16_t* Vb  = ctx;  // alias: Vb dead before attn writes ctx

    cast_x_kernel<<<dim3((MTOK * DMODEL / 4 + 255) / 256), dim3(256), 0, stream>>>(
        x, xb, (int)(MTOK * DMODEL / 4));
    transpose_w_kernel<<<dim3(32, 32, 4), dim3(32, 8), 0, stream>>>(Wq, Wk, Wv, Wo, Wt);
    // QKV: M=4096, N=3072, K=1024; 768 blocks, 3 n-strips per XCD
    gemm_bt_kernel<0><<<dim3(768), dim3(256), 0, stream>>>(
        xb, Wt, Qb, Kb, Vb, nullptr, nullptr, DMODEL, 3);
    vtrans_kernel<<<dim3(32, 32), dim3(64, 4), 0, stream>>>(Vb, Vt);
    attn_kernel<<<dim3(512), dim3(512), 0, stream>>>(Qb, Kb, Vt, ctx);
    // Out: M=4096, N=1024, K=1024; 256 blocks, 1 n-strip per XCD
    gemm_bt_kernel<1><<<dim3(256), dim3(256), 0, stream>>>(
        ctx, Wt + (size_t)3 * DMODEL * DMODEL, nullptr, nullptr, nullptr, out, bo, DMODEL, 1);
}

// Round 8
// 173.961 us; speedup vs baseline: 1.4771x; 1.0023x over previous
//
#include <hip/hip_runtime.h>
#include <hip/hip_bf16.h>

typedef __bf16 bf16_t;
typedef __bf16 bf16x8 __attribute__((ext_vector_type(8)));
typedef __bf16 bf16x4 __attribute__((ext_vector_type(4)));
typedef float  f32x4  __attribute__((ext_vector_type(4)));

#define SEQ    2048
#define BATCH  2
#define NHEAD  16
#define HDIM   64
#define DMODEL 1024
#define WIN    256
// 0.125 (1/sqrt(64)) * log2(e): folded into Q so softmax exp is one v_exp_f32
#define QSCALE 0.1803368801111244f

// async global->LDS, 16B per lane (dest = wave-uniform base + lane*16).
__device__ __forceinline__ void async_load16(const void* g, void* l) {
    __builtin_amdgcn_global_load_lds(
        (const __attribute__((address_space(1))) char*)(uintptr_t)g,
        (__attribute__((address_space(3))) char*)(uintptr_t)l, 16, 0, 0);
}

// ---------------------------------------------------------------------------
// Prep: z<4 -> transpose+cast W_z into Wt[z][n][k]; z>=4 -> cast x to bf16.
// Block (32,8).
// ---------------------------------------------------------------------------
__global__ void prep_kernel(const float* __restrict__ x,
                            const float* __restrict__ Wq, const float* __restrict__ Wk,
                            const float* __restrict__ Wv, const float* __restrict__ Wo,
                            bf16_t* __restrict__ xb, bf16_t* __restrict__ Wt) {
    __shared__ float tile[32][33];
    const int z = blockIdx.z;
    const int tx = threadIdx.x, ty = threadIdx.y;
    if (z < 4) {
        const float* W = (z == 0) ? Wq : (z == 1) ? Wk : (z == 2) ? Wv : Wo;
        bf16_t* out = Wt + (size_t)z * DMODEL * DMODEL;
        int k0 = blockIdx.y * 32, n0 = blockIdx.x * 32;
#pragma unroll
        for (int i = 0; i < 4; i++)
            tile[ty + i * 8][tx] = W[(size_t)(k0 + ty + i * 8) * DMODEL + n0 + tx];
        __syncthreads();
#pragma unroll
        for (int i = 0; i < 4; i++)
            out[(size_t)(n0 + ty + i * 8) * DMODEL + k0 + tx] = (bf16_t)tile[tx][ty + i * 8];
    } else {
        int blk = (z - 4) * 1024 + blockIdx.y * 32 + blockIdx.x;
        int i = blk * 256 + ty * 32 + tx;          // 4096*256 = 1M float4s exact
        float4 v = ((const float4*)x)[i];
        bf16x4 o;
        o[0] = (bf16_t)v.x; o[1] = (bf16_t)v.y; o[2] = (bf16_t)v.z; o[3] = (bf16_t)v.w;
        ((bf16x4*)xb)[i] = o;
    }
}

// ---------------------------------------------------------------------------
// GEMM: C = A * Bt^T, BM x 128 tile, both operands staged in LDS via
// swizzled global_load_lds (XOR chunk swizzle -> 0 bank conflicts).
// 1D grid, XCD n-strip swizzle (id&7).
// EPI 0 (BM=128): QKV epilogue. sel block-uniform; Q (scaled QSCALE) and K
//   written [B,H,S,64]; V written TRANSPOSED [B,H,64,S] via an in-LDS
//   128x128 transpose reusing the staging buffer (XOR-swizzled m-chunks).
// EPI 1: Out = acc + bo (fp32).
// ---------------------------------------------------------------------------
template <int EPI, int BM>
__global__ __launch_bounds__(256) void gemm_bt_kernel(
    const bf16_t* __restrict__ A, const bf16_t* __restrict__ Bt,
    bf16_t* __restrict__ Qb, bf16_t* __restrict__ Kb, bf16_t* __restrict__ Vt,
    float* __restrict__ Out, const float* __restrict__ bo, int K, int nPer) {
    constexpr int JN = (BM == 128) ? 4 : 2;
    __shared__ __attribute__((aligned(16))) bf16_t smem[BM * 64 + 128 * 64];
    bf16_t* As = smem;
    bf16_t* Bs = smem + BM * 64;
    const int tid = threadIdx.x;
    const int wave = tid >> 6, lane = tid & 63, quad = lane >> 4, l15 = lane & 15;
    const int wm = (BM == 128) ? (wave >> 1) : 0;
    const int wn = (BM == 128) ? (wave & 1) : wave;
    const int id = blockIdx.x, xcd = id & 7, t = id >> 3;
    const int m0 = (t / nPer) * BM, n0 = (xcd * nPer + t % nPer) * 128;

    f32x4 acc[4][JN] = {};

    for (int kt = 0; kt < K; kt += 64) {
#pragma unroll
        for (int i = 0; i < BM / 32; i++) {        // A: BM*8 chunks of 16B
            int v = tid + i * 256;
            int row = v >> 3, c = (v & 7) ^ (row & 7);
            async_load16(A + (size_t)(m0 + row) * K + kt + c * 8, (char*)As + (size_t)v * 16);
        }
#pragma unroll
        for (int i = 0; i < 4; i++) {              // B: 1024 chunks
            int v = tid + i * 256;
            int row = v >> 3, c = (v & 7) ^ (row & 7);
            async_load16(Bt + (size_t)(n0 + row) * K + kt + c * 8, (char*)Bs + (size_t)v * 16);
        }
        __syncthreads();
#pragma unroll
        for (int kk = 0; kk < 64; kk += 32) {
            bf16x8 am[4], bn[JN];
#pragma unroll
            for (int i = 0; i < 4; i++) {
                int row = wm * 64 + i * 16 + l15;
                int ch = ((kk >> 3) + quad) ^ (row & 7);
                am[i] = *(const bf16x8*)&As[row * 64 + ch * 8];
            }
#pragma unroll
            for (int j = 0; j < JN; j++) {
                int row = wn * JN * 16 + j * 16 + l15;
                int ch = ((kk >> 3) + quad) ^ (row & 7);
                bn[j] = *(const bf16x8*)&Bs[row * 64 + ch * 8];
            }
#pragma unroll
            for (int i = 0; i < 4; i++)
#pragma unroll
                for (int j = 0; j < JN; j++)
                    acc[i][j] = __builtin_amdgcn_mfma_f32_16x16x32_bf16(am[i], bn[j], acc[i][j], 0, 0, 0);
        }
        __syncthreads();
    }

    if (EPI == 1) {
#pragma unroll
        for (int i = 0; i < 4; i++)
#pragma unroll
            for (int j = 0; j < JN; j++)
#pragma unroll
                for (int r = 0; r < 4; r++) {
                    int mg = m0 + wm * 64 + i * 16 + quad * 4 + r;
                    int ng = n0 + wn * JN * 16 + j * 16 + l15;
                    Out[(size_t)mg * DMODEL + ng] = acc[i][j][r] + bo[ng];
                }
        return;
    }

    // EPI == 0 (BM==128): sel is block-uniform (128-wide n-tiles, 1024 bounds)
    const int sel = n0 >> 10;
    if (sel < 2) {
#pragma unroll
        for (int i = 0; i < 4; i++)
#pragma unroll
            for (int j = 0; j < JN; j++)
#pragma unroll
                for (int r = 0; r < 4; r++) {
                    int mg = m0 + wm * 64 + i * 16 + quad * 4 + r;
                    int ng = n0 + wn * JN * 16 + j * 16 + l15;
                    int h = (ng & 1023) >> 6, d = ng & 63;
                    int b = mg >> 11, s = mg & 2047;
                    size_t idx = ((size_t)((b * NHEAD + h) * SEQ) + s) * HDIM + d;
                    float v = acc[i][j][r];
                    if (sel == 0) Qb[idx] = (bf16_t)(v * QSCALE);
                    else          Kb[idx] = (bf16_t)v;
                }
    } else {
        // V block: in-LDS 128x128 transpose (reuse staging buffer = 32 KB),
        // then write Vt[B,H,64,S] coalesced along s.
        bf16_t* T = smem;  // element (nl, ml) at nl*128 + ((ml>>2)^(nl&31))*4 + (ml&3)
#pragma unroll
        for (int i = 0; i < 4; i++)
#pragma unroll
            for (int j = 0; j < JN; j++) {
                int nl = wn * JN * 16 + j * 16 + l15;
                int mlc = wm * 16 + i * 4 + quad;  // (ml_base>>2)
                bf16x4 p;
#pragma unroll
                for (int r = 0; r < 4; r++) p[r] = (bf16_t)acc[i][j][r];
                *(bf16x4*)&T[nl * 128 + ((mlc ^ (nl & 31)) << 2)] = p;
            }
        __syncthreads();
        const int h0 = (n0 & 1023) >> 6;
        const int b = m0 >> 11, sbase = m0 & 2047;
#pragma unroll
        for (int it = 0; it < 8; it++) {
            int idx = tid + it * 256;          // 2048 = 128 nl x 16 s-chunks
            int nl = idx >> 4, sc = idx & 15;
            bf16x4 lo = *(const bf16x4*)&T[nl * 128 + (((2 * sc) ^ (nl & 31)) << 2)];
            bf16x4 hi = *(const bf16x4*)&T[nl * 128 + (((2 * sc + 1) ^ (nl & 31)) << 2)];
            bf16x8 w;
#pragma unroll
            for (int e = 0; e < 4; e++) { w[e] = lo[e]; w[e + 4] = hi[e]; }
            int h = h0 + (nl >> 6), d = nl & 63;
            *(bf16x8*)(Vt + ((size_t)(b * NHEAD + h) * HDIM + d) * SEQ + sbase + sc * 8) = w;
        }
    }
}

// ---------------------------------------------------------------------------
// Attention (r7 structure): 512 threads, 2 query-tiles (128 q) per block;
// block stages union window (10 K/V tiles) in double-buffered LDS, each wave
// computes its 9 in-window tiles. Identity task mapping. exp2 softmax (scale
// folded into Q); denominator via ones-MFMA row-sum.
// ---------------------------------------------------------------------------
__global__ __launch_bounds__(512) void attn_kernel(
    const bf16_t* __restrict__ Qb, const bf16_t* __restrict__ Kb,
    const bf16_t* __restrict__ Vt, bf16_t* __restrict__ ctx) {
    __shared__ __attribute__((aligned(16))) bf16_t Ks[2][64 * 64];
    __shared__ __attribute__((aligned(16))) bf16_t Vs[2][64 * 64];
    __shared__ __attribute__((aligned(16))) bf16_t Plds[8][16][72];
    const int tid = threadIdx.x;
    const int wave = tid >> 6, lane = tid & 63, quad = lane >> 4, l15 = lane & 15;

    const int id = blockIdx.x;                 // id = b(1) | h(4) | qpair(4)
    const int b = id >> 8, h = (id >> 4) & 15, Q0 = (id & 15) << 7;
    const int qbase = Q0 + wave * 16;
    const int wqt = (Q0 >> 6) + (wave >> 2);   // this wave's 64-aligned q-tile

    const bf16_t* Qp = Qb + (size_t)(b * NHEAD + h) * SEQ * HDIM;
    const bf16_t* Kp = Kb + (size_t)(b * NHEAD + h) * SEQ * HDIM;
    const bf16_t* Vp = Vt + (size_t)(b * NHEAD + h) * HDIM * SEQ;

    bf16x8 qa0 = *(const bf16x8*)(Qp + (size_t)(qbase + l15) * HDIM + quad * 8);
    bf16x8 qa1 = *(const bf16x8*)(Qp + (size_t)(qbase + l15) * HDIM + 32 + quad * 8);

    bf16x8 ones;
#pragma unroll
    for (int j = 0; j < 8; j++) ones[j] = (bf16_t)1.0f;

    f32x4 O[4] = {};
    f32x4 lacc = {};

    const int base_t = Q0 >> 6;
    const int bt0 = (base_t - 4 > 0) ? base_t - 4 : 0;
    const int bt1 = (base_t + 5 < SEQ / 64 - 1) ? base_t + 5 : SEQ / 64 - 1;

    auto stage = [&](int kt, int buf) {
        const int k0 = kt * 64;
        int v = tid;                          // 512 chunks of 16B each
        int row = v >> 3, c = (v & 7) ^ (row & 7);
        async_load16(Kp + (size_t)(k0 + row) * HDIM + c * 8, (char*)&Ks[buf][0] + (size_t)v * 16);
        async_load16(Vp + (size_t)row * SEQ + k0 + c * 8, (char*)&Vs[buf][0] + (size_t)v * 16);
    };

    stage(bt0, 0);
    int cb = 0;
    for (int kt = bt0; kt <= bt1; kt++) {
        __syncthreads();                       // staging of current tile complete
        if (kt < bt1) stage(kt + 1, cb ^ 1);   // prefetch next during compute
        const int dt = kt - wqt;
        if (dt >= -4 && dt <= 4) {             // wave-uniform window check
            const int k0 = kt * 64;
            f32x4 s[4];
#pragma unroll
            for (int c = 0; c < 4; c++) {
                int row = c * 16 + l15;
                bf16x8 kb0 = *(const bf16x8*)&Ks[cb][row * 64 + (quad ^ (row & 7)) * 8];
                bf16x8 kb1 = *(const bf16x8*)&Ks[cb][row * 64 + ((quad + 4) ^ (row & 7)) * 8];
                f32x4 a = {};
                a = __builtin_amdgcn_mfma_f32_16x16x32_bf16(qa0, kb0, a, 0, 0, 0);
                a = __builtin_amdgcn_mfma_f32_16x16x32_bf16(qa1, kb1, a, 0, 0, 0);
                s[c] = a;
            }
            const bool edge = (dt == -4 || dt == 4);
#pragma unroll
            for (int c = 0; c < 4; c++)
#pragma unroll
                for (int r = 0; r < 4; r++) {
                    float sv = s[c][r];
                    if (edge) {
                        int i = qbase + quad * 4 + r;
                        int j = k0 + c * 16 + l15;
                        int dd = i - j; dd = (dd < 0) ? -dd : dd;
                        if (dd > WIN) sv = -1e30f;
                    }
                    Plds[wave][quad * 4 + r][c * 16 + l15] = (bf16_t)__builtin_exp2f(sv);
                }
            bf16x8 pa0 = *(const bf16x8*)&Plds[wave][l15][quad * 8];
            bf16x8 pa1 = *(const bf16x8*)&Plds[wave][l15][32 + quad * 8];
            lacc = __builtin_amdgcn_mfma_f32_16x16x32_bf16(pa0, ones, lacc, 0, 0, 0);
            lacc = __builtin_amdgcn_mfma_f32_16x16x32_bf16(pa1, ones, lacc, 0, 0, 0);
#pragma unroll
            for (int d = 0; d < 4; d++) {
                int row = d * 16 + l15;
                bf16x8 vb0 = *(const bf16x8*)&Vs[cb][row * 64 + (quad ^ (row & 7)) * 8];
                bf16x8 vb1 = *(const bf16x8*)&Vs[cb][row * 64 + ((quad + 4) ^ (row & 7)) * 8];
                O[d] = __builtin_amdgcn_mfma_f32_16x16x32_bf16(pa0, vb0, O[d], 0, 0, 0);
                O[d] = __builtin_amdgcn_mfma_f32_16x16x32_bf16(pa1, vb1, O[d], 0, 0, 0);
            }
        }
        __syncthreads();                       // all waves done with cb before reuse
        cb ^= 1;
    }

#pragma unroll
    for (int r = 0; r < 4; r++) {
        float inv = 1.0f / lacc[r];
        int i = qbase + quad * 4 + r;
#pragma unroll
        for (int d = 0; d < 4; d++) {
            float v = O[d][r] * inv;
            ctx[((size_t)(b * SEQ + i)) * DMODEL + h * HDIM + d * 16 + l15] = (bf16_t)v;
        }
    }
}

// ---------------------------------------------------------------------------
extern "C" void kernel_launch(void* const* d_in, const int* in_sizes, int n_in,
                              void* d_out, int out_size, void* d_ws, size_t ws_size,
                              hipStream_t stream) {
    const float* x  = (const float*)d_in[0];
    const float* Wq = (const float*)d_in[1];
    const float* Wk = (const float*)d_in[2];
    const float* Wv = (const float*)d_in[3];
    const float* Wo = (const float*)d_in[4];
    const float* bo = (const float*)d_in[5];
    float* out = (float*)d_out;

    const size_t MTOK = (size_t)BATCH * SEQ;          // 4096
    bf16_t* xb  = (bf16_t*)d_ws;                      // 4096*1024
    bf16_t* Wt  = xb + MTOK * DMODEL;                 // 4*1024*1024
    bf16_t* Qb  = Wt + (size_t)4 * DMODEL * DMODEL;   // [B,H,S,64]
    bf16_t* Kb  = Qb + MTOK * DMODEL;                 // [B,H,S,64]
    bf16_t* Vt  = Kb + MTOK * DMODEL;                 // [B,H,64,S]
    bf16_t* ctx = Vt + MTOK * DMODEL;                 // [4096][1024]

    prep_kernel<<<dim3(32, 32, 8), dim3(32, 8), 0, stream>>>(x, Wq, Wk, Wv, Wo, xb, Wt);
    // QKV: M=4096, N=3072, K=1024; 768 blocks, 3 n-strips per XCD; V fused transpose
    gemm_bt_kernel<0, 128><<<dim3(768), dim3(256), 0, stream>>>(
        xb, Wt, Qb, Kb, Vt, nullptr, nullptr, DMODEL, 3);
    attn_kernel<<<dim3(512), dim3(512), 0, stream>>>(Qb, Kb, Vt, ctx);
    // Out: M=4096, N=1024, K=1024; BM=64 -> 512 blocks, 1 n-strip per XCD
    gemm_bt_kernel<1, 64><<<dim3(512), dim3(256), 0, stream>>>(
        ctx, Wt + (size_t)3 * DMODEL * DMODEL, nullptr, nullptr, nullptr, out, bo, DMODEL, 1);
}